// Round 1
// baseline (16951.672 us; speedup 1.0000x reference)
//
#include <hip/hip_runtime.h>

#define EMB 100
#define V4_PER_ROW 25   // 100 floats = 25 float4 per row

__global__ void spmm_scatter(const float* __restrict__ vals,
                             const int* __restrict__ rows,
                             const int* __restrict__ cols,
                             const float* __restrict__ x,
                             float* __restrict__ out, int nnz) {
    long long t = (long long)blockIdx.x * blockDim.x + threadIdx.x;
    int e = (int)(t / V4_PER_ROW);
    int c = (int)(t % V4_PER_ROW);
    if (e >= nnz) return;
    int col = cols[e];
    int row = rows[e];
    float v = vals[e];
    const float4 g = *(const float4*)(x + (size_t)col * EMB + c * 4);
    float* o = out + (size_t)row * EMB + c * 4;
    atomicAdd(o + 0, v * g.x);
    atomicAdd(o + 1, v * g.y);
    atomicAdd(o + 2, v * g.z);
    atomicAdd(o + 3, v * g.w);
}

__global__ void add_inplace(float* __restrict__ acc, const float* __restrict__ x, int n4) {
    int i = blockIdx.x * blockDim.x + threadIdx.x;
    if (i < n4) {
        float4 a = ((const float4*)acc)[i];
        const float4 b = ((const float4*)x)[i];
        a.x += b.x; a.y += b.y; a.z += b.z; a.w += b.w;
        ((float4*)acc)[i] = a;
    }
}

__global__ void gather_rows(const float* __restrict__ src, const int* __restrict__ idx,
                            float* __restrict__ out, int nrows) {
    int t = blockIdx.x * blockDim.x + threadIdx.x;
    int r = t / V4_PER_ROW;
    int c = t % V4_PER_ROW;
    if (r >= nrows) return;
    int s = idx[r];
    *(float4*)(out + (size_t)r * EMB + c * 4) =
        *(const float4*)(src + (size_t)s * EMB + c * 4);
}

extern "C" void kernel_launch(void* const* d_in, const int* in_sizes, int n_in,
                              void* d_out, int out_size, void* d_ws, size_t ws_size,
                              hipStream_t stream) {
    const float* adj_vals       = (const float*)d_in[0];
    const float* u_vals         = (const float*)d_in[1];
    const float* embedding      = (const float*)d_in[2];
    /* user_embedding d_in[3] only defines N_USERS */
    const int*   adj_rows       = (const int*)d_in[4];
    const int*   adj_cols       = (const int*)d_in[5];
    const int*   u_rows         = (const int*)d_in[6];
    const int*   u_cols         = (const int*)d_in[7];
    const int*   user           = (const int*)d_in[8];

    const int NNZ_A  = in_sizes[0];
    const int NNZ_U  = in_sizes[1];
    const int N_ITEMS = in_sizes[2] / EMB;   // 100000
    const int N_USERS = in_sizes[3] / EMB;   // 40000
    const int BATCH   = in_sizes[8];         // 4096

    float* total    = (float*)d_out;                         // N_ITEMS*EMB
    float* out_user = total + (size_t)N_ITEMS * EMB;         // BATCH*EMB

    float* buf0 = (float*)d_ws;                              // N_ITEMS*EMB
    float* buf1 = buf0 + (size_t)N_ITEMS * EMB;              // N_ITEMS*EMB
    float* user_all = buf1;  // reused after layer 3 (N_USERS*EMB fits)

    const size_t itemBytes = (size_t)N_ITEMS * EMB * sizeof(float);
    const size_t userBytes = (size_t)N_USERS * EMB * sizeof(float);

    // total = embedding (layer 0 term)
    hipMemcpyAsync(total, embedding, itemBytes, hipMemcpyDeviceToDevice, stream);

    const int blkA   = (NNZ_A * V4_PER_ROW + 255) / 256;
    const int blkU   = (NNZ_U * V4_PER_ROW + 255) / 256;
    const int n4     = N_ITEMS * EMB / 4;
    const int blkAdd = (n4 + 255) / 256;

    // Layer 1: buf0 = A @ embedding ; total += buf0
    hipMemsetAsync(buf0, 0, itemBytes, stream);
    spmm_scatter<<<blkA, 256, 0, stream>>>(adj_vals, adj_rows, adj_cols, embedding, buf0, NNZ_A);
    add_inplace<<<blkAdd, 256, 0, stream>>>(total, buf0, n4);

    // Layer 2: buf1 = A @ buf0 ; total += buf1
    hipMemsetAsync(buf1, 0, itemBytes, stream);
    spmm_scatter<<<blkA, 256, 0, stream>>>(adj_vals, adj_rows, adj_cols, buf0, buf1, NNZ_A);
    add_inplace<<<blkAdd, 256, 0, stream>>>(total, buf1, n4);

    // Layer 3: buf0 = A @ buf1 ; total += buf0
    hipMemsetAsync(buf0, 0, itemBytes, stream);
    spmm_scatter<<<blkA, 256, 0, stream>>>(adj_vals, adj_rows, adj_cols, buf1, buf0, NNZ_A);
    add_inplace<<<blkAdd, 256, 0, stream>>>(total, buf0, n4);

    // user_all = U @ total  (buf1 is free now)
    hipMemsetAsync(user_all, 0, userBytes, stream);
    spmm_scatter<<<blkU, 256, 0, stream>>>(u_vals, u_rows, u_cols, total, user_all, NNZ_U);

    // out_user = user_all[user]
    gather_rows<<<(BATCH * V4_PER_ROW + 255) / 256, 256, 0, stream>>>(user_all, user, out_user, BATCH);
}

// Round 2
// 1800.849 us; speedup vs baseline: 9.4132x; 9.4132x over previous
//
#include <hip/hip_runtime.h>

#define EMB 100
#define V4_PER_ROW 25

// ---------------- CSR build kernels ----------------

__global__ void hist_rows(const int* __restrict__ rows, int* __restrict__ count, int nnz) {
    for (int e = blockIdx.x * blockDim.x + threadIdx.x; e < nnz; e += gridDim.x * blockDim.x)
        atomicAdd(&count[rows[e]], 1);
}

// single-workgroup exclusive scan of n counts into out[0..n]; out[n] = total
__global__ void exclusive_scan_single(const int* __restrict__ in, int* __restrict__ out, int n) {
    __shared__ int part[1024];
    const int tid = threadIdx.x;
    const int chunk = (n + 1023) / 1024;
    const int begin = min(tid * chunk, n);
    const int end = min(begin + chunk, n);
    int s = 0;
    for (int i = begin; i < end; ++i) s += in[i];
    part[tid] = s;
    __syncthreads();
    for (int off = 1; off < 1024; off <<= 1) {
        int v = (tid >= off) ? part[tid - off] : 0;
        __syncthreads();
        part[tid] += v;
        __syncthreads();
    }
    int run = (tid == 0) ? 0 : part[tid - 1];
    for (int i = begin; i < end; ++i) {
        out[i] = run;
        run += in[i];
    }
    if (tid == 1023) out[n] = part[1023];
}

__global__ void scatter_sorted(const float* __restrict__ vals, const int* __restrict__ rows,
                               const int* __restrict__ cols, int* __restrict__ cursor,
                               float* __restrict__ svals, int* __restrict__ scols, int nnz) {
    for (int e = blockIdx.x * blockDim.x + threadIdx.x; e < nnz; e += gridDim.x * blockDim.x) {
        int r = rows[e];
        int p = atomicAdd(&cursor[r], 1);
        svals[p] = vals[e];
        scols[p] = cols[e];
    }
}

// ---------------- CSR SpMM: one wave per row, no atomics ----------------
// lane t owns emb dims {t, t+64 (if t<EMB-64)}; optional fused total-accumulate.
__global__ __launch_bounds__(256) void spmm_csr(const float* __restrict__ vals,
                                                const int* __restrict__ cols,
                                                const int* __restrict__ rowptr,
                                                const float* __restrict__ x,
                                                float* __restrict__ out,
                                                float* __restrict__ total, int nrows) {
    const int wid = (blockIdx.x * blockDim.x + threadIdx.x) >> 6;
    const int lane = threadIdx.x & 63;
    if (wid >= nrows) return;
    const int start = rowptr[wid], end = rowptr[wid + 1];
    float acc0 = 0.f, acc1 = 0.f;
    for (int j = start; j < end; ++j) {
        const int c = cols[j];
        const float v = vals[j];
        const float* xr = x + (size_t)c * EMB;
        acc0 += v * xr[lane];
        if (lane < EMB - 64) acc1 += v * xr[64 + lane];
    }
    const size_t o = (size_t)wid * EMB + lane;
    out[o] = acc0;
    if (total) total[o] += acc0;
    if (lane < EMB - 64) {
        out[o + 64] = acc1;
        if (total) total[o + 64] += acc1;
    }
}

// CSR SpMM restricted to batched rows: one wave per batch element.
__global__ __launch_bounds__(256) void spmm_csr_batch(const float* __restrict__ vals,
                                                      const int* __restrict__ cols,
                                                      const int* __restrict__ rowptr,
                                                      const int* __restrict__ user,
                                                      const float* __restrict__ x,
                                                      float* __restrict__ out, int batch) {
    const int wid = (blockIdx.x * blockDim.x + threadIdx.x) >> 6;
    const int lane = threadIdx.x & 63;
    if (wid >= batch) return;
    const int row = user[wid];
    const int start = rowptr[row], end = rowptr[row + 1];
    float acc0 = 0.f, acc1 = 0.f;
    for (int j = start; j < end; ++j) {
        const int c = cols[j];
        const float v = vals[j];
        const float* xr = x + (size_t)c * EMB;
        acc0 += v * xr[lane];
        if (lane < EMB - 64) acc1 += v * xr[64 + lane];
    }
    const size_t o = (size_t)wid * EMB + lane;
    out[o] = acc0;
    if (lane < EMB - 64) out[o + 64] = acc1;
}

// ---------------- fallback (round-1) kernels ----------------

__global__ void spmm_scatter(const float* __restrict__ vals, const int* __restrict__ rows,
                             const int* __restrict__ cols, const float* __restrict__ x,
                             float* __restrict__ out, int nnz) {
    long long t = (long long)blockIdx.x * blockDim.x + threadIdx.x;
    int e = (int)(t / V4_PER_ROW);
    int c = (int)(t % V4_PER_ROW);
    if (e >= nnz) return;
    int col = cols[e];
    int row = rows[e];
    float v = vals[e];
    const float4 g = *(const float4*)(x + (size_t)col * EMB + c * 4);
    float* o = out + (size_t)row * EMB + c * 4;
    atomicAdd(o + 0, v * g.x);
    atomicAdd(o + 1, v * g.y);
    atomicAdd(o + 2, v * g.z);
    atomicAdd(o + 3, v * g.w);
}

__global__ void add_inplace(float* __restrict__ acc, const float* __restrict__ x, int n4) {
    int i = blockIdx.x * blockDim.x + threadIdx.x;
    if (i < n4) {
        float4 a = ((const float4*)acc)[i];
        const float4 b = ((const float4*)x)[i];
        a.x += b.x; a.y += b.y; a.z += b.z; a.w += b.w;
        ((float4*)acc)[i] = a;
    }
}

__global__ void gather_rows(const float* __restrict__ src, const int* __restrict__ idx,
                            float* __restrict__ out, int nrows) {
    int t = blockIdx.x * blockDim.x + threadIdx.x;
    int r = t / V4_PER_ROW;
    int c = t % V4_PER_ROW;
    if (r >= nrows) return;
    int s = idx[r];
    *(float4*)(out + (size_t)r * EMB + c * 4) = *(const float4*)(src + (size_t)s * EMB + c * 4);
}

// ---------------- launch ----------------

static inline size_t align256(size_t x) { return (x + 255) & ~(size_t)255; }

extern "C" void kernel_launch(void* const* d_in, const int* in_sizes, int n_in,
                              void* d_out, int out_size, void* d_ws, size_t ws_size,
                              hipStream_t stream) {
    const float* adj_vals  = (const float*)d_in[0];
    const float* u_vals    = (const float*)d_in[1];
    const float* embedding = (const float*)d_in[2];
    const int*   adj_rows  = (const int*)d_in[4];
    const int*   adj_cols  = (const int*)d_in[5];
    const int*   u_rows    = (const int*)d_in[6];
    const int*   u_cols    = (const int*)d_in[7];
    const int*   user      = (const int*)d_in[8];

    const int NNZ_A   = in_sizes[0];
    const int NNZ_U   = in_sizes[1];
    const int N_ITEMS = in_sizes[2] / EMB;
    const int N_USERS = in_sizes[3] / EMB;
    const int BATCH   = in_sizes[8];

    float* total    = (float*)d_out;
    float* out_user = total + (size_t)N_ITEMS * EMB;

    const size_t itemBytes = (size_t)N_ITEMS * EMB * sizeof(float);

    // ---- fast-path workspace layout ----
    size_t off = 0;
    char* ws = (char*)d_ws;
    #define WS_ALLOC(name, bytes) char* name = ws + off; off += align256(bytes)
    WS_ALLOC(p_buf0,    itemBytes);
    WS_ALLOC(p_buf1,    itemBytes);
    WS_ALLOC(p_avals,   (size_t)NNZ_A * 4);
    WS_ALLOC(p_acols,   (size_t)NNZ_A * 4);
    WS_ALLOC(p_arowptr, ((size_t)N_ITEMS + 1) * 4);
    WS_ALLOC(p_acursor, (size_t)N_ITEMS * 4);
    WS_ALLOC(p_uvals,   (size_t)NNZ_U * 4);
    WS_ALLOC(p_ucols,   (size_t)NNZ_U * 4);
    WS_ALLOC(p_urowptr, ((size_t)N_USERS + 1) * 4);
    WS_ALLOC(p_ucursor, (size_t)N_USERS * 4);
    #undef WS_ALLOC

    if (ws_size >= off) {
        // ================= fast path: CSR-ize, then gather-SpMM =================
        float* buf0 = (float*)p_buf0;
        float* buf1 = (float*)p_buf1;
        float* a_svals = (float*)p_avals;
        int*   a_scols = (int*)p_acols;
        int*   a_rowptr = (int*)p_arowptr;
        int*   a_cursor = (int*)p_acursor;
        float* u_svals = (float*)p_uvals;
        int*   u_scols = (int*)p_ucols;
        int*   u_rowptr = (int*)p_urowptr;
        int*   u_cursor = (int*)p_ucursor;

        hipMemcpyAsync(total, embedding, itemBytes, hipMemcpyDeviceToDevice, stream);

        // build A CSR
        hipMemsetAsync(a_cursor, 0, (size_t)N_ITEMS * 4, stream);
        hist_rows<<<1024, 256, 0, stream>>>(adj_rows, a_cursor, NNZ_A);
        exclusive_scan_single<<<1, 1024, 0, stream>>>(a_cursor, a_rowptr, N_ITEMS);
        hipMemcpyAsync(a_cursor, a_rowptr, (size_t)N_ITEMS * 4, hipMemcpyDeviceToDevice, stream);
        scatter_sorted<<<1024, 256, 0, stream>>>(adj_vals, adj_rows, adj_cols,
                                                 a_cursor, a_svals, a_scols, NNZ_A);

        // build U CSR
        hipMemsetAsync(u_cursor, 0, (size_t)N_USERS * 4, stream);
        hist_rows<<<1024, 256, 0, stream>>>(u_rows, u_cursor, NNZ_U);
        exclusive_scan_single<<<1, 1024, 0, stream>>>(u_cursor, u_rowptr, N_USERS);
        hipMemcpyAsync(u_cursor, u_rowptr, (size_t)N_USERS * 4, hipMemcpyDeviceToDevice, stream);
        scatter_sorted<<<1024, 256, 0, stream>>>(u_vals, u_rows, u_cols,
                                                 u_cursor, u_svals, u_scols, NNZ_U);

        const int rowsPerBlk = 256 / 64;
        const int gridA = (N_ITEMS + rowsPerBlk - 1) / rowsPerBlk;

        // layers: x_{k+1} = A x_k ; total += x_{k+1} (fused)
        spmm_csr<<<gridA, 256, 0, stream>>>(a_svals, a_scols, a_rowptr, embedding, buf0, total, N_ITEMS);
        spmm_csr<<<gridA, 256, 0, stream>>>(a_svals, a_scols, a_rowptr, buf0, buf1, total, N_ITEMS);
        spmm_csr<<<gridA, 256, 0, stream>>>(a_svals, a_scols, a_rowptr, buf1, buf0, total, N_ITEMS);

        // user rows only (4096 of 40000)
        const int gridB = (BATCH + rowsPerBlk - 1) / rowsPerBlk;
        spmm_csr_batch<<<gridB, 256, 0, stream>>>(u_svals, u_scols, u_rowptr, user, total, out_user, BATCH);
    } else {
        // ================= fallback: round-1 atomic path =================
        float* buf0 = (float*)d_ws;
        float* buf1 = buf0 + (size_t)N_ITEMS * EMB;
        float* user_all = buf1;
        const size_t userBytes = (size_t)N_USERS * EMB * sizeof(float);

        hipMemcpyAsync(total, embedding, itemBytes, hipMemcpyDeviceToDevice, stream);

        const int blkA = (NNZ_A * V4_PER_ROW + 255) / 256;
        const int blkU = (NNZ_U * V4_PER_ROW + 255) / 256;
        const int n4 = N_ITEMS * EMB / 4;
        const int blkAdd = (n4 + 255) / 256;

        hipMemsetAsync(buf0, 0, itemBytes, stream);
        spmm_scatter<<<blkA, 256, 0, stream>>>(adj_vals, adj_rows, adj_cols, embedding, buf0, NNZ_A);
        add_inplace<<<blkAdd, 256, 0, stream>>>(total, buf0, n4);

        hipMemsetAsync(buf1, 0, itemBytes, stream);
        spmm_scatter<<<blkA, 256, 0, stream>>>(adj_vals, adj_rows, adj_cols, buf0, buf1, NNZ_A);
        add_inplace<<<blkAdd, 256, 0, stream>>>(total, buf1, n4);

        hipMemsetAsync(buf0, 0, itemBytes, stream);
        spmm_scatter<<<blkA, 256, 0, stream>>>(adj_vals, adj_rows, adj_cols, buf1, buf0, NNZ_A);
        add_inplace<<<blkAdd, 256, 0, stream>>>(total, buf0, n4);

        hipMemsetAsync(user_all, 0, userBytes, stream);
        spmm_scatter<<<blkU, 256, 0, stream>>>(u_vals, u_rows, u_cols, total, user_all, NNZ_U);
        gather_rows<<<(BATCH * V4_PER_ROW + 255) / 256, 256, 0, stream>>>(user_all, user, out_user, BATCH);
    }
}

// Round 3
// 980.870 us; speedup vs baseline: 17.2823x; 1.8360x over previous
//
#include <hip/hip_runtime.h>
#include <stdint.h>

#define EMB 100
#define HW 50            // packed bf16 words (2 elems each) per row
#define V4_PER_ROW 25

// ---------------- bf16 helpers ----------------
static __device__ __forceinline__ uint32_t pack_bf16(float a, float b) {
    uint32_t ua = __float_as_uint(a);
    uint32_t ub = __float_as_uint(b);
    ua = (ua + 0x7FFFu + ((ua >> 16) & 1u)) >> 16;
    ub = (ub + 0x7FFFu + ((ub >> 16) & 1u)) >> 16;
    return ua | (ub << 16);
}
static __device__ __forceinline__ float bflo(uint32_t p) { return __uint_as_float(p << 16); }
static __device__ __forceinline__ float bfhi(uint32_t p) { return __uint_as_float(p & 0xFFFF0000u); }

// ---------------- convert fp32 row-major -> packed bf16 ----------------
__global__ void convert_bf16(const float2* __restrict__ x, uint32_t* __restrict__ xbf, int nwords) {
    for (int i = blockIdx.x * blockDim.x + threadIdx.x; i < nwords; i += gridDim.x * blockDim.x) {
        float2 v = x[i];
        xbf[i] = pack_bf16(v.x, v.y);
    }
}

// ---------------- CSR build: fused A+U histogram ----------------
__global__ void hist_both(const int* __restrict__ ra, int na,
                          const int* __restrict__ ru, int nu,
                          int* __restrict__ ca, int* __restrict__ cu) {
    const int n = na + nu;
    for (int e = blockIdx.x * blockDim.x + threadIdx.x; e < n; e += gridDim.x * blockDim.x) {
        if (e < na) atomicAdd(&ca[__builtin_nontemporal_load(ra + e)], 1);
        else        atomicAdd(&cu[__builtin_nontemporal_load(ru + (e - na))], 1);
    }
}

// ---------------- 3-phase exclusive scan ----------------
#define SCAN_T 256
#define SCAN_E 16   // 4096 elems per block

__global__ void scan_blocks(const int* __restrict__ in, int* __restrict__ out,
                            int* __restrict__ sums, int n) {
    __shared__ int smem[SCAN_T];
    const int b = blockIdx.x, tid = threadIdx.x;
    const int base = b * SCAN_T * SCAN_E + tid * SCAN_E;
    int loc[SCAN_E];
    int s = 0;
    for (int i = 0; i < SCAN_E; ++i) {
        int idx = base + i;
        int v = (idx < n) ? in[idx] : 0;
        loc[i] = s; s += v;
    }
    smem[tid] = s; __syncthreads();
    for (int off = 1; off < SCAN_T; off <<= 1) {
        int v = (tid >= off) ? smem[tid - off] : 0;
        __syncthreads();
        smem[tid] += v;
        __syncthreads();
    }
    int pre = (tid == 0) ? 0 : smem[tid - 1];
    if (tid == SCAN_T - 1) sums[b] = smem[tid];
    for (int i = 0; i < SCAN_E; ++i) {
        int idx = base + i;
        if (idx < n) out[idx] = pre + loc[i];
    }
}

// single wave inclusive-scan of <=64 block sums; also writes rowptr[n]=nnz
__global__ void scan_sums(int* __restrict__ sums, int nb, int* __restrict__ rowptr_end, int total) {
    int tid = threadIdx.x;
    int v = (tid < nb) ? sums[tid] : 0;
    for (int off = 1; off < 64; off <<= 1) {
        int u = __shfl_up(v, off);
        if (tid >= off) v += u;
    }
    if (tid < nb) sums[tid] = v;
    if (tid == 0) *rowptr_end = total;
}

__global__ void scan_fixup(int* __restrict__ out, const int* __restrict__ sums, int n) {
    const int b = blockIdx.x;
    if (b == 0) return;
    const int add = sums[b - 1];
    const int base = b * SCAN_T * SCAN_E + threadIdx.x * SCAN_E;
    for (int i = 0; i < SCAN_E; ++i) {
        int idx = base + i;
        if (idx < n) out[idx] += add;
    }
}

// ---------------- fused A+U scatter into packed (val,col) CSR ----------------
__global__ void scatter_both(const float* __restrict__ va, const int* __restrict__ ra,
                             const int* __restrict__ ia, int na,
                             const float* __restrict__ vu, const int* __restrict__ ru,
                             const int* __restrict__ iu, int nu,
                             int* __restrict__ curA, int* __restrict__ curU,
                             uint64_t* __restrict__ svcA, uint64_t* __restrict__ svcU) {
    const int n = na + nu;
    for (int e = blockIdx.x * blockDim.x + threadIdx.x; e < n; e += gridDim.x * blockDim.x) {
        if (e < na) {
            int r = __builtin_nontemporal_load(ra + e);
            int p = atomicAdd(&curA[r], 1);
            uint64_t w = ((uint64_t)(uint32_t)__builtin_nontemporal_load(ia + e) << 32)
                       | (uint32_t)__float_as_uint(__builtin_nontemporal_load(va + e));
            svcA[p] = w;
        } else {
            int k = e - na;
            int r = __builtin_nontemporal_load(ru + k);
            int p = atomicAdd(&curU[r], 1);
            uint64_t w = ((uint64_t)(uint32_t)__builtin_nontemporal_load(iu + k) << 32)
                       | (uint32_t)__float_as_uint(__builtin_nontemporal_load(vu + k));
            svcU[p] = w;
        }
    }
}

// ---------------- CSR SpMM, bf16 gathers, wave per row ----------------
// layers 1/2: outbf = pack(acc).  layer 3 (total2!=null):
//   total = emb + up(x1bf) + up(x2bf) + acc;  totbf = pack(total)
__global__ __launch_bounds__(256) void spmm_bf16(
    const uint64_t* __restrict__ svc, const int* __restrict__ rowptr,
    const uint32_t* __restrict__ xbf,
    uint32_t* __restrict__ outbf,
    const float2* __restrict__ emb2, const uint32_t* __restrict__ x1bf,
    const uint32_t* __restrict__ x2bf,
    float2* __restrict__ total2, uint32_t* __restrict__ totbf,
    int nrows)
{
    const int wid = (blockIdx.x * blockDim.x + threadIdx.x) >> 6;
    const int lane = threadIdx.x & 63;
    if (wid >= nrows) return;
    const int start = rowptr[wid], end = rowptr[wid + 1];
    float a0 = 0.f, a1 = 0.f;
    for (int base = start; base < end; base += 64) {
        const int nc = min(64, end - base);
        uint64_t w = 0;
        if (lane < nc) w = __builtin_nontemporal_load(svc + base + lane);
        float myv = __uint_as_float((uint32_t)w);
        int myc = (int)(uint32_t)(w >> 32);
        int t = 0;
        for (; t + 2 <= nc; t += 2) {
            float v0 = __shfl(myv, t), v1 = __shfl(myv, t + 1);
            int c0 = __shfl(myc, t), c1 = __shfl(myc, t + 1);
            uint32_t p0 = 0, p1 = 0;
            if (lane < HW) {
                p0 = xbf[(size_t)c0 * HW + lane];
                p1 = xbf[(size_t)c1 * HW + lane];
            }
            a0 = fmaf(v0, bflo(p0), a0); a1 = fmaf(v0, bfhi(p0), a1);
            a0 = fmaf(v1, bflo(p1), a0); a1 = fmaf(v1, bfhi(p1), a1);
        }
        if (t < nc) {
            float v0 = __shfl(myv, t);
            int c0 = __shfl(myc, t);
            uint32_t p0 = 0;
            if (lane < HW) p0 = xbf[(size_t)c0 * HW + lane];
            a0 = fmaf(v0, bflo(p0), a0);
            a1 = fmaf(v0, bfhi(p0), a1);
        }
    }
    if (lane < HW) {
        const size_t widx = (size_t)wid * HW + lane;
        if (outbf) outbf[widx] = pack_bf16(a0, a1);
        if (total2) {
            float2 e = emb2[widx];
            uint32_t w1 = x1bf[widx], w2 = x2bf[widx];
            float t0 = e.x + bflo(w1) + bflo(w2) + a0;
            float t1 = e.y + bfhi(w1) + bfhi(w2) + a1;
            total2[widx] = make_float2(t0, t1);
            totbf[widx] = pack_bf16(t0, t1);
        }
    }
}

__global__ __launch_bounds__(256) void spmm_batch_bf16(
    const uint64_t* __restrict__ svc, const int* __restrict__ rowptr,
    const int* __restrict__ user, const uint32_t* __restrict__ xbf,
    float2* __restrict__ out2, int batch)
{
    const int wid = (blockIdx.x * blockDim.x + threadIdx.x) >> 6;
    const int lane = threadIdx.x & 63;
    if (wid >= batch) return;
    const int row = user[wid];
    const int start = rowptr[row], end = rowptr[row + 1];
    float a0 = 0.f, a1 = 0.f;
    for (int base = start; base < end; base += 64) {
        const int nc = min(64, end - base);
        uint64_t w = 0;
        if (lane < nc) w = __builtin_nontemporal_load(svc + base + lane);
        float myv = __uint_as_float((uint32_t)w);
        int myc = (int)(uint32_t)(w >> 32);
        int t = 0;
        for (; t + 2 <= nc; t += 2) {
            float v0 = __shfl(myv, t), v1 = __shfl(myv, t + 1);
            int c0 = __shfl(myc, t), c1 = __shfl(myc, t + 1);
            uint32_t p0 = 0, p1 = 0;
            if (lane < HW) {
                p0 = xbf[(size_t)c0 * HW + lane];
                p1 = xbf[(size_t)c1 * HW + lane];
            }
            a0 = fmaf(v0, bflo(p0), a0); a1 = fmaf(v0, bfhi(p0), a1);
            a0 = fmaf(v1, bflo(p1), a0); a1 = fmaf(v1, bfhi(p1), a1);
        }
        if (t < nc) {
            float v0 = __shfl(myv, t);
            int c0 = __shfl(myc, t);
            uint32_t p0 = 0;
            if (lane < HW) p0 = xbf[(size_t)c0 * HW + lane];
            a0 = fmaf(v0, bflo(p0), a0);
            a1 = fmaf(v0, bfhi(p0), a1);
        }
    }
    if (lane < HW) out2[(size_t)wid * HW + lane] = make_float2(a0, a1);
}

// ---------------- fallback (round-1) kernels ----------------
__global__ void spmm_scatter(const float* __restrict__ vals, const int* __restrict__ rows,
                             const int* __restrict__ cols, const float* __restrict__ x,
                             float* __restrict__ out, int nnz) {
    long long t = (long long)blockIdx.x * blockDim.x + threadIdx.x;
    int e = (int)(t / V4_PER_ROW);
    int c = (int)(t % V4_PER_ROW);
    if (e >= nnz) return;
    int col = cols[e]; int row = rows[e]; float v = vals[e];
    const float4 g = *(const float4*)(x + (size_t)col * EMB + c * 4);
    float* o = out + (size_t)row * EMB + c * 4;
    atomicAdd(o + 0, v * g.x); atomicAdd(o + 1, v * g.y);
    atomicAdd(o + 2, v * g.z); atomicAdd(o + 3, v * g.w);
}
__global__ void add_inplace(float* __restrict__ acc, const float* __restrict__ x, int n4) {
    int i = blockIdx.x * blockDim.x + threadIdx.x;
    if (i < n4) {
        float4 a = ((const float4*)acc)[i];
        const float4 b = ((const float4*)x)[i];
        a.x += b.x; a.y += b.y; a.z += b.z; a.w += b.w;
        ((float4*)acc)[i] = a;
    }
}
__global__ void gather_rows(const float* __restrict__ src, const int* __restrict__ idx,
                            float* __restrict__ out, int nrows) {
    int t = blockIdx.x * blockDim.x + threadIdx.x;
    int r = t / V4_PER_ROW, c = t % V4_PER_ROW;
    if (r >= nrows) return;
    int s = idx[r];
    *(float4*)(out + (size_t)r * EMB + c * 4) = *(const float4*)(src + (size_t)s * EMB + c * 4);
}

// ---------------- launch ----------------
static inline size_t align256(size_t x) { return (x + 255) & ~(size_t)255; }

extern "C" void kernel_launch(void* const* d_in, const int* in_sizes, int n_in,
                              void* d_out, int out_size, void* d_ws, size_t ws_size,
                              hipStream_t stream) {
    const float* adj_vals  = (const float*)d_in[0];
    const float* u_vals    = (const float*)d_in[1];
    const float* embedding = (const float*)d_in[2];
    const int*   adj_rows  = (const int*)d_in[4];
    const int*   adj_cols  = (const int*)d_in[5];
    const int*   u_rows    = (const int*)d_in[6];
    const int*   u_cols    = (const int*)d_in[7];
    const int*   user      = (const int*)d_in[8];

    const int NNZ_A   = in_sizes[0];
    const int NNZ_U   = in_sizes[1];
    const int N_ITEMS = in_sizes[2] / EMB;
    const int N_USERS = in_sizes[3] / EMB;
    const int BATCH   = in_sizes[8];

    float* total    = (float*)d_out;
    float* out_user = total + (size_t)N_ITEMS * EMB;

    // ---- workspace layout ----
    size_t off = 0;
    char* ws = (char*)d_ws;
    #define WS_ALLOC(name, bytes) char* name = ws + off; off += align256(bytes)
    WS_ALLOC(p_x1bf,   (size_t)N_ITEMS * HW * 4);
    WS_ALLOC(p_x2bf,   (size_t)N_ITEMS * HW * 4);
    WS_ALLOC(p_ebf,    (size_t)N_ITEMS * HW * 4);   // embbf; reused as totbf after L3
    WS_ALLOC(p_svcA,   (size_t)NNZ_A * 8);
    WS_ALLOC(p_svcU,   (size_t)NNZ_U * 8);
    WS_ALLOC(p_rpA,    ((size_t)N_ITEMS + 1) * 4);
    WS_ALLOC(p_curA,   (size_t)N_ITEMS * 4);
    WS_ALLOC(p_rpU,    ((size_t)N_USERS + 1) * 4);
    WS_ALLOC(p_curU,   (size_t)N_USERS * 4);
    WS_ALLOC(p_sumsA,  64 * 4);
    WS_ALLOC(p_sumsU,  64 * 4);
    #undef WS_ALLOC

    if (ws_size >= off) {
        uint32_t* x1bf  = (uint32_t*)p_x1bf;
        uint32_t* x2bf  = (uint32_t*)p_x2bf;
        uint32_t* embbf = (uint32_t*)p_ebf;
        uint32_t* totbf = (uint32_t*)p_ebf;   // alias: embbf dead after layer 1
        uint64_t* svcA  = (uint64_t*)p_svcA;
        uint64_t* svcU  = (uint64_t*)p_svcU;
        int* rpA  = (int*)p_rpA;  int* curA = (int*)p_curA;
        int* rpU  = (int*)p_rpU;  int* curU = (int*)p_curU;
        int* sumsA = (int*)p_sumsA; int* sumsU = (int*)p_sumsU;

        const int nbA = (N_ITEMS + SCAN_T * SCAN_E - 1) / (SCAN_T * SCAN_E);
        const int nbU = (N_USERS + SCAN_T * SCAN_E - 1) / (SCAN_T * SCAN_E);

        // embedding -> packed bf16 (consumed by layer 1)
        convert_bf16<<<2048, 256, 0, stream>>>((const float2*)embedding, embbf, N_ITEMS * HW);

        // histograms (A and U fused)
        hipMemsetAsync(curA, 0, (size_t)N_ITEMS * 4, stream);
        hipMemsetAsync(curU, 0, (size_t)N_USERS * 4, stream);
        hist_both<<<2048, 256, 0, stream>>>(adj_rows, NNZ_A, u_rows, NNZ_U, curA, curU);

        // exclusive scans -> rowptrs
        scan_blocks<<<nbA, SCAN_T, 0, stream>>>(curA, rpA, sumsA, N_ITEMS);
        scan_sums<<<1, 64, 0, stream>>>(sumsA, nbA, rpA + N_ITEMS, NNZ_A);
        scan_fixup<<<nbA, SCAN_T, 0, stream>>>(rpA, sumsA, N_ITEMS);
        scan_blocks<<<nbU, SCAN_T, 0, stream>>>(curU, rpU, sumsU, N_USERS);
        scan_sums<<<1, 64, 0, stream>>>(sumsU, nbU, rpU + N_USERS, NNZ_U);
        scan_fixup<<<nbU, SCAN_T, 0, stream>>>(rpU, sumsU, N_USERS);

        // cursors = copy of rowptr; fused scatter into packed (val,col)
        hipMemcpyAsync(curA, rpA, (size_t)N_ITEMS * 4, hipMemcpyDeviceToDevice, stream);
        hipMemcpyAsync(curU, rpU, (size_t)N_USERS * 4, hipMemcpyDeviceToDevice, stream);
        scatter_both<<<2048, 256, 0, stream>>>(adj_vals, adj_rows, adj_cols, NNZ_A,
                                               u_vals, u_rows, u_cols, NNZ_U,
                                               curA, curU, svcA, svcU);

        const int gridA = (N_ITEMS + 3) / 4;   // 4 waves (rows) per 256-thread block
        // L1: x1 = A emb
        spmm_bf16<<<gridA, 256, 0, stream>>>(svcA, rpA, embbf, x1bf,
                                             nullptr, nullptr, nullptr, nullptr, nullptr, N_ITEMS);
        // L2: x2 = A x1
        spmm_bf16<<<gridA, 256, 0, stream>>>(svcA, rpA, x1bf, x2bf,
                                             nullptr, nullptr, nullptr, nullptr, nullptr, N_ITEMS);
        // L3: acc = A x2 ; total = emb + x1 + x2 + acc ; totbf = pack(total)
        spmm_bf16<<<gridA, 256, 0, stream>>>(svcA, rpA, x2bf, nullptr,
                                             (const float2*)embedding, x1bf, x2bf,
                                             (float2*)total, totbf, N_ITEMS);
        // user rows: out_user = (U @ total)[user]
        const int gridB = (BATCH + 3) / 4;
        spmm_batch_bf16<<<gridB, 256, 0, stream>>>(svcU, rpU, user, totbf,
                                                   (float2*)out_user, BATCH);
    } else {
        // ---- fallback: round-1 atomic path (needs 2*itemBytes) ----
        const size_t itemBytes = (size_t)N_ITEMS * EMB * sizeof(float);
        float* buf0 = (float*)d_ws;
        float* buf1 = buf0 + (size_t)N_ITEMS * EMB;
        float* user_all = buf1;
        const size_t userBytes = (size_t)N_USERS * EMB * sizeof(float);

        hipMemcpyAsync(total, embedding, itemBytes, hipMemcpyDeviceToDevice, stream);
        const int blkA = (NNZ_A * V4_PER_ROW + 255) / 256;
        const int blkU = (NNZ_U * V4_PER_ROW + 255) / 256;
        const int n4 = N_ITEMS * EMB / 4;
        const int blkAdd = (n4 + 255) / 256;

        hipMemsetAsync(buf0, 0, itemBytes, stream);
        spmm_scatter<<<blkA, 256, 0, stream>>>(adj_vals, adj_rows, adj_cols, embedding, buf0, NNZ_A);
        add_inplace<<<blkAdd, 256, 0, stream>>>(total, buf0, n4);
        hipMemsetAsync(buf1, 0, itemBytes, stream);
        spmm_scatter<<<blkA, 256, 0, stream>>>(adj_vals, adj_rows, adj_cols, buf0, buf1, NNZ_A);
        add_inplace<<<blkAdd, 256, 0, stream>>>(total, buf1, n4);
        hipMemsetAsync(buf0, 0, itemBytes, stream);
        spmm_scatter<<<blkA, 256, 0, stream>>>(adj_vals, adj_rows, adj_cols, buf1, buf0, NNZ_A);
        add_inplace<<<blkAdd, 256, 0, stream>>>(total, buf0, n4);
        hipMemsetAsync(user_all, 0, userBytes, stream);
        spmm_scatter<<<blkU, 256, 0, stream>>>(u_vals, u_rows, u_cols, total, user_all, NNZ_U);
        gather_rows<<<(BATCH * V4_PER_ROW + 255) / 256, 256, 0, stream>>>(user_all, user, out_user, BATCH);
    }
}